// Round 1
// baseline (1352.992 us; speedup 1.0000x reference)
//
#include <hip/hip_runtime.h>
#include <hip/hip_bf16.h>

#define BB 8
#define ND 12288
#define NU 49152
#define CI 64
#define CO 32
#define SP 9
#define NNZ 147456

// pooled scratch: [B][NU][CI] f32 = 100,663,296 bytes in d_ws
#define POOLED_BYTES ((size_t)BB * NU * CI * sizeof(float))

__global__ __launch_bounds__(256) void scatter_kernel(
    const float* __restrict__ x, const int* __restrict__ rows,
    const int* __restrict__ cols, const float* __restrict__ vals,
    float* __restrict__ pooled)
{
    const int t = blockIdx.x * 256 + threadIdx.x;
    const int i = t >> 4;          // nnz entry
    const int c = (t & 15) << 2;   // channel quad
    const int row = rows[i];
    const int col = cols[i];
    const float v = vals[i];
#pragma unroll
    for (int b = 0; b < BB; ++b) {
        const float4 xv = *(const float4*)(x + ((size_t)(b * ND + col) * CI + c));
        float* p = pooled + ((size_t)(b * NU + row) * CI + c);
        atomicAdd(p + 0, xv.x * v);
        atomicAdd(p + 1, xv.y * v);
        atomicAdd(p + 2, xv.z * v);
        atomicAdd(p + 3, xv.w * v);
    }
}

// conv: block = 256 threads = 4 waves; wave owns 32 vertices x 32 out-channels.
// lane = vq*8 + oq ; vq in 0..7 (4 vertices each), oq in 0..7 (4 channels each).
// Per spiral step s: stage wT[c][o] (shared) and per-wave transposed gT[c][v],
// rows padded to 36 floats: ds_read_b128 stays 16B-aligned (36*4=144 = 16*9)
// and vq/oq stride-4 bank pattern tiles all 32 banks conflict-free.
__global__ __launch_bounds__(256) void conv_kernel(
    const float* __restrict__ pooled, const int* __restrict__ spiral,
    const float* __restrict__ weight, const float* __restrict__ bias,
    float* __restrict__ out)
{
    __shared__ __align__(16) float wT[64][36];
    __shared__ __align__(16) float gT[4][64][36];

    const int tid  = threadIdx.x;
    const int w    = tid >> 6;
    const int lane = tid & 63;
    const int vq   = lane >> 3;   // 0..7
    const int oq   = lane & 7;    // 0..7
    const int m0   = blockIdx.x * 128;      // flattened (b*NU + n), block-contiguous
    const int b    = m0 / NU;               // NU % 128 == 0 -> same b for whole block
    const int n_b  = m0 - b * NU;           // mesh-vertex of local v=0

    const int rsub = lane >> 4;             // 0..3 (staging row within quad)
    const int c4   = (lane & 15) << 2;      // 0..60 (staging channel quad)

    float acc[4][4];
#pragma unroll
    for (int i = 0; i < 4; ++i)
#pragma unroll
        for (int j = 0; j < 4; ++j) acc[i][j] = 0.f;

    for (int s = 0; s < SP; ++s) {
        __syncthreads();   // previous iteration's compute done before restaging
        // stage weight chunk: wT[c][o] = weight[o][s*64+c]  (2048 elems)
#pragma unroll
        for (int j = 0; j < 8; ++j) {
            const int idx = tid + j * 256;
            const int o = idx >> 6, c = idx & 63;
            wT[c][o] = weight[o * (SP * CI) + s * CI + c];
        }
        // stage gathered chunk, transposed: gT[w][c][vloc]
#pragma unroll
        for (int p = 0; p < 8; ++p) {
            const int vloc = p * 4 + rsub;
            const int n    = n_b + w * 32 + vloc;
            const int gidx = spiral[n * SP + s];
            const float4 pv =
                *(const float4*)(pooled + ((size_t)(b * NU + gidx) * CI + c4));
            gT[w][c4 + 0][vloc] = pv.x;
            gT[w][c4 + 1][vloc] = pv.y;
            gT[w][c4 + 2][vloc] = pv.z;
            gT[w][c4 + 3][vloc] = pv.w;
        }
        __syncthreads();
        // compute: 64 k-steps, 2x ds_read_b128 + 16 FMA per lane per k
#pragma unroll 8
        for (int k = 0; k < 64; ++k) {
            const float4 g4 = *(const float4*)&gT[w][k][vq * 4];
            const float4 w4 = *(const float4*)&wT[k][oq * 4];
            const float gv[4] = {g4.x, g4.y, g4.z, g4.w};
            const float wv[4] = {w4.x, w4.y, w4.z, w4.w};
#pragma unroll
            for (int i = 0; i < 4; ++i)
#pragma unroll
                for (int j = 0; j < 4; ++j)
                    acc[i][j] += gv[i] * wv[j];
        }
    }

    // epilogue: bias + relu, coalesced float4 stores
    float bo[4];
#pragma unroll
    for (int j = 0; j < 4; ++j) bo[j] = bias[oq * 4 + j];
#pragma unroll
    for (int i = 0; i < 4; ++i) {
        const int m = m0 + w * 32 + vq * 4 + i;
        float4 r;
        r.x = fmaxf(acc[i][0] + bo[0], 0.f);
        r.y = fmaxf(acc[i][1] + bo[1], 0.f);
        r.z = fmaxf(acc[i][2] + bo[2], 0.f);
        r.w = fmaxf(acc[i][3] + bo[3], 0.f);
        *(float4*)(out + (size_t)m * CO + oq * 4) = r;
    }
}

extern "C" void kernel_launch(void* const* d_in, const int* in_sizes, int n_in,
                              void* d_out, int out_size, void* d_ws, size_t ws_size,
                              hipStream_t stream) {
    const float* x       = (const float*)d_in[0];
    const int*   rows    = (const int*)d_in[1];
    const int*   cols    = (const int*)d_in[2];
    const float* vals    = (const float*)d_in[3];
    const int*   spiral  = (const int*)d_in[4];
    const float* weight  = (const float*)d_in[5];
    const float* bias    = (const float*)d_in[6];
    float*       out     = (float*)d_out;
    float*       pooled  = (float*)d_ws;

    // zero the pooled accumulator (ws is poisoned 0xAA before every call)
    hipMemsetAsync(pooled, 0, POOLED_BYTES, stream);

    // scatter: NNZ*16 threads
    scatter_kernel<<<(NNZ * 16) / 256, 256, 0, stream>>>(x, rows, cols, vals, pooled);

    // conv: 128 vertices per block over B*NU flattened rows
    conv_kernel<<<(BB * NU) / 128, 256, 0, stream>>>(pooled, spiral, weight, bias, out);
}

// Round 2
// 427.078 us; speedup vs baseline: 3.1680x; 3.1680x over previous
//
#include <hip/hip_runtime.h>
#include <hip/hip_bf16.h>

#define BB 8
#define ND 12288
#define NU 49152
#define CI 64
#define CO 32
#define SP 9
#define NNZ 147456

// ---- workspace layout ----
// pooled : [B][NU][CI] f32              = 100,663,296 B
// cnt    : [NU] int                     =     196,608 B
// start  : [NU+1] int                   =     196,612 B (padded to 196,616)
// fill   : [NU] int                     =     196,608 B
// pcol   : [NNZ] int                    =     589,824 B
// pval   : [NNZ] f32                    =     589,824 B
#define POOLED_BYTES ((size_t)BB * NU * CI * sizeof(float))
#define OFF_CNT   (POOLED_BYTES)
#define OFF_START (OFF_CNT   + (size_t)NU * 4)
#define OFF_FILL  (OFF_START + (size_t)(NU + 1) * 4 + 4)
#define OFF_PCOL  (OFF_FILL  + (size_t)NU * 4)
#define OFF_PVAL  (OFF_PCOL  + (size_t)NNZ * 4)

__global__ __launch_bounds__(256) void hist_kernel(
    const int* __restrict__ rows, int* __restrict__ cnt)
{
    const int i = blockIdx.x * 256 + threadIdx.x;
    atomicAdd(&cnt[rows[i]], 1);
}

// single block, 1024 threads; each thread owns NU/1024 = 48 contiguous rows.
__global__ __launch_bounds__(1024) void scan_kernel(
    const int* __restrict__ cnt, int* __restrict__ start, int* __restrict__ fill)
{
    __shared__ int sums[1024];
    const int t = threadIdx.x;
    const int base = t * (NU / 1024);
    int s = 0;
#pragma unroll
    for (int i = 0; i < NU / 1024; ++i) s += cnt[base + i];
    sums[t] = s;
    __syncthreads();
    for (int off = 1; off < 1024; off <<= 1) {
        const int add = (t >= off) ? sums[t - off] : 0;
        __syncthreads();
        sums[t] += add;
        __syncthreads();
    }
    int excl = sums[t] - s;
#pragma unroll
    for (int i = 0; i < NU / 1024; ++i) {
        const int c = cnt[base + i];
        start[base + i] = excl;
        fill[base + i]  = excl;
        excl += c;
    }
    if (t == 1023) start[NU] = sums[1023];
}

__global__ __launch_bounds__(256) void perm_kernel(
    const int* __restrict__ rows, const int* __restrict__ cols,
    const float* __restrict__ vals, int* __restrict__ fill,
    int* __restrict__ pcol, float* __restrict__ pval)
{
    const int i = blockIdx.x * 256 + threadIdx.x;
    const int pos = atomicAdd(&fill[rows[i]], 1);
    pcol[pos] = cols[i];
    pval[pos] = vals[i];
}

// one thread per (row, channel-quad): gather this row's entries, write pooled once.
__global__ __launch_bounds__(256) void pool_kernel(
    const float* __restrict__ x, const int* __restrict__ start,
    const int* __restrict__ pcol, const float* __restrict__ pval,
    float* __restrict__ pooled)
{
    const int t   = blockIdx.x * 256 + threadIdx.x;
    const int row = t >> 4;
    const int cq  = (t & 15) << 2;
    const int s = start[row], e = start[row + 1];
    float4 acc[BB];
#pragma unroll
    for (int b = 0; b < BB; ++b) acc[b] = make_float4(0.f, 0.f, 0.f, 0.f);
    for (int j = s; j < e; ++j) {
        const int col = pcol[j];
        const float v = pval[j];
#pragma unroll
        for (int b = 0; b < BB; ++b) {
            const float4 xv = *(const float4*)(x + ((size_t)(b * ND + col) * CI + cq));
            acc[b].x = fmaf(v, xv.x, acc[b].x);
            acc[b].y = fmaf(v, xv.y, acc[b].y);
            acc[b].z = fmaf(v, xv.z, acc[b].z);
            acc[b].w = fmaf(v, xv.w, acc[b].w);
        }
    }
#pragma unroll
    for (int b = 0; b < BB; ++b)
        *(float4*)(pooled + ((size_t)(b * NU + row) * CI + cq)) = acc[b];
}

// conv: block = 256 threads = 4 waves; wave owns 32 vertices x 32 out-channels.
__global__ __launch_bounds__(256) void conv_kernel(
    const float* __restrict__ pooled, const int* __restrict__ spiral,
    const float* __restrict__ weight, const float* __restrict__ bias,
    float* __restrict__ out)
{
    __shared__ __align__(16) float wT[64][36];
    __shared__ __align__(16) float gT[4][64][36];

    const int tid  = threadIdx.x;
    const int w    = tid >> 6;
    const int lane = tid & 63;
    const int vq   = lane >> 3;
    const int oq   = lane & 7;
    const int m0   = blockIdx.x * 128;
    const int b    = m0 / NU;
    const int n_b  = m0 - b * NU;

    const int rsub = lane >> 4;
    const int c4   = (lane & 15) << 2;

    float acc[4][4];
#pragma unroll
    for (int i = 0; i < 4; ++i)
#pragma unroll
        for (int j = 0; j < 4; ++j) acc[i][j] = 0.f;

    for (int s = 0; s < SP; ++s) {
        __syncthreads();
#pragma unroll
        for (int j = 0; j < 8; ++j) {
            const int idx = tid + j * 256;
            const int o = idx >> 6, c = idx & 63;
            wT[c][o] = weight[o * (SP * CI) + s * CI + c];
        }
#pragma unroll
        for (int p = 0; p < 8; ++p) {
            const int vloc = p * 4 + rsub;
            const int n    = n_b + w * 32 + vloc;
            const int gidx = spiral[n * SP + s];
            const float4 pv =
                *(const float4*)(pooled + ((size_t)(b * NU + gidx) * CI + c4));
            gT[w][c4 + 0][vloc] = pv.x;
            gT[w][c4 + 1][vloc] = pv.y;
            gT[w][c4 + 2][vloc] = pv.z;
            gT[w][c4 + 3][vloc] = pv.w;
        }
        __syncthreads();
#pragma unroll 8
        for (int k = 0; k < 64; ++k) {
            const float4 g4 = *(const float4*)&gT[w][k][vq * 4];
            const float4 w4 = *(const float4*)&wT[k][oq * 4];
            const float gv[4] = {g4.x, g4.y, g4.z, g4.w};
            const float wv[4] = {w4.x, w4.y, w4.z, w4.w};
#pragma unroll
            for (int i = 0; i < 4; ++i)
#pragma unroll
                for (int j = 0; j < 4; ++j)
                    acc[i][j] += gv[i] * wv[j];
        }
    }

    float bo[4];
#pragma unroll
    for (int j = 0; j < 4; ++j) bo[j] = bias[oq * 4 + j];
#pragma unroll
    for (int i = 0; i < 4; ++i) {
        const int m = m0 + w * 32 + vq * 4 + i;
        float4 r;
        r.x = fmaxf(acc[i][0] + bo[0], 0.f);
        r.y = fmaxf(acc[i][1] + bo[1], 0.f);
        r.z = fmaxf(acc[i][2] + bo[2], 0.f);
        r.w = fmaxf(acc[i][3] + bo[3], 0.f);
        *(float4*)(out + (size_t)m * CO + oq * 4) = r;
    }
}

extern "C" void kernel_launch(void* const* d_in, const int* in_sizes, int n_in,
                              void* d_out, int out_size, void* d_ws, size_t ws_size,
                              hipStream_t stream) {
    const float* x      = (const float*)d_in[0];
    const int*   rows   = (const int*)d_in[1];
    const int*   cols   = (const int*)d_in[2];
    const float* vals   = (const float*)d_in[3];
    const int*   spiral = (const int*)d_in[4];
    const float* weight = (const float*)d_in[5];
    const float* bias   = (const float*)d_in[6];
    float*       out    = (float*)d_out;

    char* ws = (char*)d_ws;
    float* pooled = (float*)ws;
    int*   cnt    = (int*)(ws + OFF_CNT);
    int*   startp = (int*)(ws + OFF_START);
    int*   fill   = (int*)(ws + OFF_FILL);
    int*   pcol   = (int*)(ws + OFF_PCOL);
    float* pval   = (float*)(ws + OFF_PVAL);

    // zero only the histogram bins (pooled is fully overwritten by pool_kernel)
    hipMemsetAsync(cnt, 0, (size_t)NU * 4, stream);

    hist_kernel<<<NNZ / 256, 256, 0, stream>>>(rows, cnt);
    scan_kernel<<<1, 1024, 0, stream>>>(cnt, startp, fill);
    perm_kernel<<<NNZ / 256, 256, 0, stream>>>(rows, cols, vals, fill, pcol, pval);
    pool_kernel<<<(NU * 16) / 256, 256, 0, stream>>>(x, startp, pcol, pval, pooled);

    conv_kernel<<<(BB * NU) / 128, 256, 0, stream>>>(pooled, spiral, weight, bias, out);
}

// Round 3
// 323.258 us; speedup vs baseline: 4.1855x; 1.3212x over previous
//
#include <hip/hip_runtime.h>
#include <hip/hip_bf16.h>

#define BB 8
#define ND 12288
#define NU 49152
#define CI 64
#define CO 32
#define SP 9
#define NNZ 147456
#define KTOT (SP * CI)   // 576

using short8 = __attribute__((ext_vector_type(8))) short;
using f32x4  = __attribute__((ext_vector_type(4))) float;

// ---- workspace layout ----
// pooled_bf : [B][NU][CI] bf16 = 50,331,648 B
// wbf       : [CO][KTOT] bf16  =     36,864 B
// cnt/start/fill/pcol/pval     : CSR scratch
#define OFF_WBF   ((size_t)BB * NU * CI * 2)
#define OFF_CNT   (OFF_WBF   + (size_t)CO * KTOT * 2)
#define OFF_START (OFF_CNT   + (size_t)NU * 4)
#define OFF_FILL  (OFF_START + (size_t)(NU + 1) * 4 + 4)
#define OFF_PCOL  (OFF_FILL  + (size_t)NU * 4)
#define OFF_PVAL  (OFF_PCOL  + (size_t)NNZ * 4)

static __device__ __forceinline__ unsigned short f2bf(float f) {
    __hip_bfloat16 h = __float2bfloat16(f);   // RNE
    return *reinterpret_cast<unsigned short*>(&h);
}

__global__ __launch_bounds__(256) void hist_kernel(
    const int* __restrict__ rows, int* __restrict__ cnt)
{
    const int i = blockIdx.x * 256 + threadIdx.x;
    atomicAdd(&cnt[rows[i]], 1);
}

__global__ __launch_bounds__(1024) void scan_kernel(
    const int* __restrict__ cnt, int* __restrict__ start, int* __restrict__ fill)
{
    __shared__ int sums[1024];
    const int t = threadIdx.x;
    const int base = t * (NU / 1024);
    int s = 0;
#pragma unroll
    for (int i = 0; i < NU / 1024; ++i) s += cnt[base + i];
    sums[t] = s;
    __syncthreads();
    for (int off = 1; off < 1024; off <<= 1) {
        const int add = (t >= off) ? sums[t - off] : 0;
        __syncthreads();
        sums[t] += add;
        __syncthreads();
    }
    int excl = sums[t] - s;
#pragma unroll
    for (int i = 0; i < NU / 1024; ++i) {
        const int c = cnt[base + i];
        start[base + i] = excl;
        fill[base + i]  = excl;
        excl += c;
    }
    if (t == 1023) start[NU] = sums[1023];
}

__global__ __launch_bounds__(256) void perm_kernel(
    const int* __restrict__ rows, const int* __restrict__ cols,
    const float* __restrict__ vals, int* __restrict__ fill,
    int* __restrict__ pcol, float* __restrict__ pval)
{
    const int i = blockIdx.x * 256 + threadIdx.x;
    const int pos = atomicAdd(&fill[rows[i]], 1);
    pcol[pos] = cols[i];
    pval[pos] = vals[i];
}

// weight f32 [CO][KTOT] -> bf16 [CO][KTOT] (same [o][k] layout)
__global__ __launch_bounds__(256) void wcvt_kernel(
    const float* __restrict__ weight, unsigned short* __restrict__ wbf)
{
    const int i = blockIdx.x * 256 + threadIdx.x;
    wbf[i] = f2bf(weight[i]);
}

// one thread per (row, channel-quad): gather entries, f32 accumulate, bf16 store.
__global__ __launch_bounds__(256) void pool_kernel(
    const float* __restrict__ x, const int* __restrict__ start,
    const int* __restrict__ pcol, const float* __restrict__ pval,
    unsigned short* __restrict__ pooled)
{
    const int t   = blockIdx.x * 256 + threadIdx.x;
    const int row = t >> 4;
    const int cq  = (t & 15) << 2;
    const int s = start[row], e = start[row + 1];
    float4 acc[BB];
#pragma unroll
    for (int b = 0; b < BB; ++b) acc[b] = make_float4(0.f, 0.f, 0.f, 0.f);
    for (int j = s; j < e; ++j) {
        const int col = pcol[j];
        const float v = pval[j];
#pragma unroll
        for (int b = 0; b < BB; ++b) {
            const float4 xv = *(const float4*)(x + ((size_t)(b * ND + col) * CI + cq));
            acc[b].x = fmaf(v, xv.x, acc[b].x);
            acc[b].y = fmaf(v, xv.y, acc[b].y);
            acc[b].z = fmaf(v, xv.z, acc[b].z);
            acc[b].w = fmaf(v, xv.w, acc[b].w);
        }
    }
#pragma unroll
    for (int b = 0; b < BB; ++b) {
        uint2 pk;
        pk.x = (unsigned)f2bf(acc[b].x) | ((unsigned)f2bf(acc[b].y) << 16);
        pk.y = (unsigned)f2bf(acc[b].z) | ((unsigned)f2bf(acc[b].w) << 16);
        *(uint2*)(pooled + ((size_t)(b * NU + row) * CI + cq)) = pk;
    }
}

// MFMA conv: wave handles 16 rows x 32 out-channels, K=576, no LDS.
// A-frag: lane(r=lane&15, kg=lane>>4) holds pooled[gidx(r)][k-chunk], 16B global load.
// B-frag: wbf[o=nt*16+r][k-chunk], 16B global load (36KB, L1-resident).
// C/D: col=lane&15, row=(lane>>4)*4+reg (HW-verified layout).
__global__ __launch_bounds__(256) void conv_mfma(
    const unsigned short* __restrict__ pooled, const unsigned short* __restrict__ wbf,
    const int* __restrict__ spiral, const float* __restrict__ bias,
    float* __restrict__ out)
{
    const int tid  = threadIdx.x;
    const int w    = tid >> 6;
    const int lane = tid & 63;
    const int r    = lane & 15;
    const int kg   = lane >> 4;
    const int m0   = blockIdx.x * 64 + w * 16;   // 64 rows/block; NU%64==0 -> same b
    const int b    = m0 / NU;
    const int n0   = m0 - b * NU;
    const size_t poolb = (size_t)b * NU * CI;

    f32x4 acc0 = {0.f, 0.f, 0.f, 0.f};
    f32x4 acc1 = {0.f, 0.f, 0.f, 0.f};

    const int n = n0 + r;
    const unsigned short* w0 = wbf + (size_t)r        * KTOT + kg * 8;
    const unsigned short* w1 = wbf + (size_t)(16 + r) * KTOT + kg * 8;

#pragma unroll
    for (int s = 0; s < SP; ++s) {
        const int gidx = spiral[n * SP + s];
        const short8* arow = (const short8*)(pooled + poolb + (size_t)gidx * CI);
        const short8 a0 = arow[kg];       // c = kg*8 .. +7        (k 0..31)
        const short8 a1 = arow[4 + kg];   // c = 32 + kg*8 .. +7   (k 32..63)
        const short8 b00 = *(const short8*)(w0 + s * 64);
        const short8 b01 = *(const short8*)(w1 + s * 64);
        const short8 b10 = *(const short8*)(w0 + s * 64 + 32);
        const short8 b11 = *(const short8*)(w1 + s * 64 + 32);
        acc0 = __builtin_amdgcn_mfma_f32_16x16x32_bf16(a0, b00, acc0, 0, 0, 0);
        acc1 = __builtin_amdgcn_mfma_f32_16x16x32_bf16(a0, b01, acc1, 0, 0, 0);
        acc0 = __builtin_amdgcn_mfma_f32_16x16x32_bf16(a1, b10, acc0, 0, 0, 0);
        acc1 = __builtin_amdgcn_mfma_f32_16x16x32_bf16(a1, b11, acc1, 0, 0, 0);
    }

    const float bo0 = bias[r];
    const float bo1 = bias[16 + r];
#pragma unroll
    for (int reg = 0; reg < 4; ++reg) {
        const int m = m0 + kg * 4 + reg;
        out[(size_t)m * CO + r]      = fmaxf(acc0[reg] + bo0, 0.f);
        out[(size_t)m * CO + 16 + r] = fmaxf(acc1[reg] + bo1, 0.f);
    }
}

extern "C" void kernel_launch(void* const* d_in, const int* in_sizes, int n_in,
                              void* d_out, int out_size, void* d_ws, size_t ws_size,
                              hipStream_t stream) {
    const float* x      = (const float*)d_in[0];
    const int*   rows   = (const int*)d_in[1];
    const int*   cols   = (const int*)d_in[2];
    const float* vals   = (const float*)d_in[3];
    const int*   spiral = (const int*)d_in[4];
    const float* weight = (const float*)d_in[5];
    const float* bias   = (const float*)d_in[6];
    float*       out    = (float*)d_out;

    char* ws = (char*)d_ws;
    unsigned short* pooled = (unsigned short*)ws;
    unsigned short* wbf    = (unsigned short*)(ws + OFF_WBF);
    int*   cnt    = (int*)(ws + OFF_CNT);
    int*   startp = (int*)(ws + OFF_START);
    int*   fill   = (int*)(ws + OFF_FILL);
    int*   pcol   = (int*)(ws + OFF_PCOL);
    float* pval   = (float*)(ws + OFF_PVAL);

    hipMemsetAsync(cnt, 0, (size_t)NU * 4, stream);

    hist_kernel<<<NNZ / 256, 256, 0, stream>>>(rows, cnt);
    scan_kernel<<<1, 1024, 0, stream>>>(cnt, startp, fill);
    perm_kernel<<<NNZ / 256, 256, 0, stream>>>(rows, cols, vals, fill, pcol, pval);
    wcvt_kernel<<<(CO * KTOT) / 256, 256, 0, stream>>>(weight, wbf);
    pool_kernel<<<(NU * 16) / 256, 256, 0, stream>>>(x, startp, pcol, pval, pooled);

    conv_mfma<<<(BB * NU) / 64, 256, 0, stream>>>(pooled, wbf, spiral, bias, out);
}